// Round 6
// baseline (342.495 us; speedup 1.0000x reference)
//
#include <hip/hip_runtime.h>
#include <cstdint>
#include <cstddef>

constexpr int N = 40000;
constexpr int E = 640000;
constexpr int D = 128;
constexpr int NBKT = 157;               // dst-buckets of 256 rows each
constexpr int BCAP = 5120;              // per-bucket capacity: mean 4096, +16 sigma
constexpr int AGG_GRID = 2500;          // x16 quarters = exactly N row slots
constexpr int NSLICE = 4;               // 32-col slices; 2.56 MB each -> L2-resident
constexpr size_t SLICE_H  = (size_t)N * 32;   // halfs per slice  (1,280,000)
constexpr size_t SLICE_D  = (size_t)N * 16;   // dwords per slice (640,000)
constexpr size_t SLICE_H8 = (size_t)N * 4;    // half8s per slice (160,000)

typedef _Float16 half8 __attribute__((ext_vector_type(8)));
typedef _Float16 half2v __attribute__((ext_vector_type(2)));
typedef float f32x4 __attribute__((ext_vector_type(4)));
typedef float f32x2 __attribute__((ext_vector_type(2)));
typedef unsigned long long ull;

__device__ __forceinline__ unsigned int pack_rec(int idx, float v) {
  union { _Float16 h; unsigned short us; } c; c.h = (_Float16)v;
  return (unsigned int)idx | ((unsigned int)c.us << 16);
}

// ------- zero region (contiguous): sums4 32768 | hist 256 | histcur 256 |
//         bktcnt 640 | done 256 = 34,176 B = 2136 uint4 -------

__global__ void k_zero(uint4* __restrict__ p) {
  int i = blockIdx.x * 256 + threadIdx.x;
  if (i < 2136) p[i] = make_uint4(0u, 0u, 0u, 0u);
}

// ---- fused prep: dst-bucket partition (blocks 0..156, 16 edges/thread)
//      overlapped with xconv (157..2656, SLICE-MAJOR output) and wconv
//      (2657..2912). record = src:16 | dstlocal:8 | wfix27. ----

__global__ void k_bigprep(const int* __restrict__ ei, const float* __restrict__ ew,
                          const float* __restrict__ X, _Float16* __restrict__ Xh,
                          const float* __restrict__ W, _Float16* __restrict__ Wt,
                          ull* __restrict__ binned, int* __restrict__ bktcnt) {
  int bid = blockIdx.x, t = threadIdx.x;
  if (bid < NBKT) {                       // partition: 16 edges per thread
    __shared__ int lhist[NBKT], lbase[NBKT], lrank[NBKT];
    if (t < NBKT) { lhist[t] = 0; lrank[t] = 0; }
    __syncthreads();
    int e16 = bid * 256 + t;
    bool act = (e16 < E / 16);            // E/16 = 40000
    int4 s4[4], d4[4]; float4 w4[4];
    if (act) {
#pragma unroll
      for (int u = 0; u < 4; ++u) {
        s4[u] = ((const int4*)ei)[e16 * 4 + u];
        d4[u] = ((const int4*)(ei + E))[e16 * 4 + u];
        w4[u] = ((const float4*)ew)[e16 * 4 + u];
      }
#pragma unroll
      for (int u = 0; u < 4; ++u) {
        atomicAdd(&lhist[d4[u].x >> 8], 1); atomicAdd(&lhist[d4[u].y >> 8], 1);
        atomicAdd(&lhist[d4[u].z >> 8], 1); atomicAdd(&lhist[d4[u].w >> 8], 1);
      }
    }
    __syncthreads();
    if (t < NBKT && lhist[t] > 0) lbase[t] = atomicAdd(&bktcnt[t], lhist[t]);
    __syncthreads();
    if (act) {
      auto emit = [&](int s, int dcol, float w) {
        int bkt = dcol >> 8;
        int rank = atomicAdd(&lrank[bkt], 1);
        int pos = lbase[bkt] + rank;
        ull rec = (ull)(unsigned)(s & 0xFFFF)
                | ((ull)(unsigned)(dcol & 255) << 16)
                | ((ull)__float2uint_rn(w * 67108864.0f) << 24);   // wfix27
        if (pos < BCAP) binned[(size_t)bkt * BCAP + pos] = rec;
      };
#pragma unroll
      for (int u = 0; u < 4; ++u) {
        emit(s4[u].x, d4[u].x, w4[u].x); emit(s4[u].y, d4[u].y, w4[u].y);
        emit(s4[u].z, d4[u].z, w4[u].z); emit(s4[u].w, d4[u].w, w4[u].w);
      }
    }
  } else if (bid < 2657) {                // X -> fp16, 8 elems/thread, slice-major
    int i = (bid - NBKT) * 256 + t;       // < 640,000
    float4 v0 = ((const float4*)X)[i * 2];
    float4 v1 = ((const float4*)X)[i * 2 + 1];
    half8 h;
    h[0] = (_Float16)v0.x; h[1] = (_Float16)v0.y; h[2] = (_Float16)v0.z; h[3] = (_Float16)v0.w;
    h[4] = (_Float16)v1.x; h[5] = (_Float16)v1.y; h[6] = (_Float16)v1.z; h[7] = (_Float16)v1.w;
    int r = i >> 4, c8 = i & 15;          // row, 8-col group
    ((half8*)Xh)[(size_t)(c8 >> 2) * SLICE_H8 + (size_t)r * 4 + (c8 & 3)] = h;
  } else {                                // W transpose+convert: Wt[l][c][k] = W[l][k][c]
    int o = (bid - 2657) * 256 + t;       // < 65,536
    int l = o >> 14, rem = o & 16383, c = rem >> 7, k = rem & 127;
    Wt[o] = (_Float16)W[l * 16384 + k * 128 + c];
  }
}

// ---- per-bucket stats (rebuild degree via LDS u64 atomics) + LAST-BLOCK
//      FINALIZE (bsum scan + hist suffix-scan in the 157th block). ----

__global__ __launch_bounds__(256) void k_bstats(const ull* __restrict__ binned,
    const int* __restrict__ bktcnt, float* __restrict__ dis, int* __restrict__ rowc,
    int* __restrict__ bsum, int* __restrict__ hist, int* __restrict__ bpre,
    int* __restrict__ histcur, unsigned int* __restrict__ done) {
  __shared__ ull acc[256];
  __shared__ int lhist[64];
  __shared__ int red[256];
  __shared__ int amlast;
  int bkt = blockIdx.x, t = threadIdx.x;
  acc[t] = 0ULL;
  if (t < 64) lhist[t] = 0;
  __syncthreads();
  int cnt = min(bktcnt[bkt], BCAP);
  const ull* bp = binned + (size_t)bkt * BCAP;
  for (int e = t; e < cnt; e += 256) {
    ull r = bp[e];
    int local = (int)((r >> 16) & 255);
    atomicAdd(&acc[local], (1ULL << 40) | (r >> 24));   // count | wfix sum
  }
  __syncthreads();
  int row = bkt * 256 + t;
  int c = 0;
  if (row < N) {
    ull a = acc[t];
    c = (int)(a >> 40) + 1;                             // +1: self-loop
    float deg = (float)(a & ((1ULL << 40) - 1)) * (1.0f / 67108864.0f);
    dis[row] = rsqrtf(deg + 1.0f);                      // +1 = self-loop weight
    rowc[row] = c;
    atomicAdd(&lhist[min(c, 63)], 1);
  }
  red[t] = c;
  __syncthreads();
  for (int off = 128; off > 0; off >>= 1) {
    if (t < off) red[t] += red[t + off];
    __syncthreads();
  }
  if (t == 0) bsum[bkt] = red[0];
  if (t < 64 && lhist[t] > 0) atomicAdd(&hist[t], lhist[t]);
  __syncthreads();
  if (t == 0) {
    __threadfence();
    amlast = (atomicAdd(done, 1u) == NBKT - 1);
  }
  __syncthreads();
  if (!amlast) return;
  __threadfence();
  red[t] = (t < NBKT) ? bsum[t] : 0;
  __syncthreads();
  for (int off = 1; off < 256; off <<= 1) {
    int v = red[t];
    int add = (t >= off) ? red[t - off] : 0;
    __syncthreads();
    red[t] = v + add;
    __syncthreads();
  }
  if (t < NBKT) bpre[t] = (t == 0) ? 0 : red[t - 1];
  if (t < 64) {
    int s = 0;
    for (int b2 = t + 1; b2 < 64; ++b2) s += hist[b2];
    histcur[t] = s;
  }
}

// ------- GEMM body (MFMA fp16; BN+cvt on A load; slice-major in AND out) -------

__device__ __forceinline__ void gemm_body(int bid, int tid, const _Float16* __restrict__ X,
    const _Float16* __restrict__ Wt, const float* __restrict__ sums,
    const float* __restrict__ gamma, const float* __restrict__ beta, int useBN,
    const float* __restrict__ dis, _Float16* __restrict__ Hout,
    float* scl, float* shf) {
  if (tid < 128) {
    if (useBN) {   // derive BN scale/shift from replicated sums (2 KB, L2-hot)
      float s = 0.f, s2 = 0.f;
#pragma unroll
      for (int r = 0; r < 8; ++r) { s += sums[r * 256 + tid]; s2 += sums[r * 256 + 128 + tid]; }
      float mu = s * (1.0f / N);
      float var = s2 * (1.0f / N) - mu * mu;
      float rs = rsqrtf(var + 1e-5f);
      float sc = gamma[tid] * rs;
      scl[tid] = sc;
      shf[tid] = beta[tid] - mu * sc;
    } else {
      scl[tid] = 1.0f;
      shf[tid] = 0.0f;
    }
  }
  __syncthreads();

  int wv = tid >> 6, lane = tid & 63;
  int fr = lane & 15, kg = lane >> 4;
  int arow = bid * 64 + wv * 16 + fr;

  half8 af[4];
#pragma unroll
  for (int kc = 0; kc < 4; ++kc) {        // kc == input slice (32 cols)
    int k0 = kc * 32 + kg * 8;
    half8 xr = *(const half8*)&X[(size_t)kc * SLICE_H + (size_t)arow * 32 + kg * 8];
    half8 a;
#pragma unroll
    for (int u = 0; u < 8; ++u)
      a[u] = (_Float16)fmaf((float)xr[u], scl[k0 + u], shf[k0 + u]);
    af[kc] = a;
  }

  f32x4 acc[8];
#pragma unroll
  for (int ct = 0; ct < 8; ++ct) acc[ct] = (f32x4){0.f, 0.f, 0.f, 0.f};

#pragma unroll
  for (int ct = 0; ct < 8; ++ct) {
    const _Float16* wcol = Wt + (size_t)(ct * 16 + fr) * 128;
#pragma unroll
    for (int kc = 0; kc < 4; ++kc) {
      half8 bf = *(const half8*)&wcol[kc * 32 + kg * 8];
      acc[ct] = __builtin_amdgcn_mfma_f32_16x16x32_f16(af[kc], bf, acc[ct], 0, 0, 0);
    }
  }

  int orow0 = bid * 64 + wv * 16 + kg * 4;
#pragma unroll
  for (int rg = 0; rg < 4; ++rg) {
    int grow = orow0 + rg;
    float dsv = dis[grow];                 // pre-scale by dis[src] for the gather
#pragma unroll
    for (int ct = 0; ct < 8; ++ct) {       // col = ct*16+fr -> slice ct>>1
      Hout[(size_t)(ct >> 1) * SLICE_H + (size_t)grow * 32 + (ct & 1) * 16 + fr] =
          (_Float16)(acc[ct][rg] * dsv);
    }
  }
}

__global__ __launch_bounds__(256) void k_gemm(const _Float16* __restrict__ X,
    const _Float16* __restrict__ Wt, const float* __restrict__ sums,
    const float* __restrict__ gamma, const float* __restrict__ beta, int useBN,
    const float* __restrict__ dis, _Float16* __restrict__ Hout) {
  __shared__ float scl[128], shf[128];
  gemm_body(blockIdx.x, threadIdx.x, X, Wt, sums, gamma, beta, useBN, dis, Hout, scl, shf);
}

// ---- layer-0 gemm + per-bucket CSR build + degree-sort placement ----

__global__ __launch_bounds__(256) void k_gemm0_fill(const _Float16* __restrict__ X,
    const _Float16* __restrict__ Wt, const float* __restrict__ dis,
    _Float16* __restrict__ Hout,
    const int* __restrict__ rowc, const int* __restrict__ bpre,
    const ull* __restrict__ binned, const int* __restrict__ bktcnt,
    unsigned int* __restrict__ cv, int* __restrict__ offs,
    int* __restrict__ histcur, int* __restrict__ perm) {
  int bid = blockIdx.x, t = threadIdx.x;
  if (bid < 625) {
    __shared__ float scl[128], shf[128];
    gemm_body(bid, t, X, Wt, (const float*)nullptr, (const float*)nullptr,
              (const float*)nullptr, 0, dis, Hout, scl, shf);
  } else if (bid < 625 + NBKT) {
    int bkt = bid - 625;
    __shared__ int lcur[256];
    __shared__ int s[256];
    int row = bkt * 256 + t;
    int c = (row < N) ? rowc[row] : 0;
    s[t] = c;
    __syncthreads();
    for (int off = 1; off < 256; off <<= 1) {
      int v = s[t];
      int add = (t >= off) ? s[t - off] : 0;
      __syncthreads();
      s[t] = v + add;
      __syncthreads();
    }
    int run = bpre[bkt] + s[t] - c;        // exclusive prefix
    if (row < N) {
      offs[row] = run;
      cv[run] = pack_rec(row, 1.0f);       // slot 0 = self-loop
      lcur[t] = run + 1;
    } else {
      lcur[t] = 0;
    }
    if (row == N - 1) offs[N] = N + E;
    __syncthreads();
    int cnt = min(bktcnt[bkt], BCAP);
    const ull* bp = binned + (size_t)bkt * BCAP;
    for (int e = t; e < cnt; e += 256) {
      ull r = bp[e];
      int local = (int)((r >> 16) & 255);
      int srcv = (int)(r & 0xFFFFu);
      float w = (float)(unsigned)(r >> 24) * (1.0f / 67108864.0f);
      int slot = atomicAdd(&lcur[local], 1);
      cv[slot] = pack_rec(srcv, w);
    }
  } else {
    __shared__ int lhist[64], lbase[64];
    if (t < 64) lhist[t] = 0;
    __syncthreads();
    int i = (bid - (625 + NBKT)) * 256 + t;
    bool valid = (i < N);
    int bin = 0, myrank = 0;
    if (valid) {
      int c = rowc[i];
      bin = min(c, 63);
      myrank = atomicAdd(&lhist[bin], 1);
    }
    __syncthreads();
    if (t < 64 && lhist[t] > 0) lbase[t] = atomicAdd(&histcur[t], lhist[t]);
    __syncthreads();
    if (valid) perm[lbase[bin] + myrank] = i;
  }
}

// ---- Aggregation + skip + (optional) fused BN stats — COLUMN-SLICED ----
// Grid = NSLICE x AGG_GRID, slice-major: slice s's 2500 blocks run as a phase;
// the 2.56 MB slice of hlin becomes resident in every XCD's 4 MB L2, so the
// random per-edge gathers (dword/lane, 64 B/quarter, line-packed slice-major
// layout) are L2-served instead of Infinity-Cache-served. Streaming operands
// (cv, x0, f32 out) use non-temporal accesses to protect slice residency.
// Per-column FMA order over edges is unchanged -> same arithmetic as before.

__global__ __launch_bounds__(256) void k_agg(const unsigned int* __restrict__ Hu,
    const int* __restrict__ offs, const unsigned int* __restrict__ cv,
    const float* __restrict__ dis, const float* __restrict__ bias,
    const unsigned int* __restrict__ x0u, const int* __restrict__ perm,
    int doRelu, int doStats, int outF32,
    unsigned int* __restrict__ Hout16, float* __restrict__ Houtf,
    float* __restrict__ sums) {
  int t = threadIdx.x;
  int blk = blockIdx.x % AGG_GRID;       // row-block
  int slice = blockIdx.x / AGG_GRID;     // 0..3
  int sl = t & 15;                       // lane within quarter
  int g = t >> 4;                        // quarter id 0..15
  int row = perm[blk * 16 + g];          // degree-sorted row for this quarter
  int C0 = slice * 32;
  float bvx = bias[C0 + sl * 2];
  float bvy = bias[C0 + sl * 2 + 1];
  const unsigned int* hb = Hu + (size_t)slice * SLICE_D + sl;

  int e0 = offs[row], e1 = offs[row + 1];
  float a0 = 0.f, a1 = 0.f;
  for (int eb = e0; eb < e1; eb += 16) {
    int m = min(16, e1 - eb);            // >= 1 (self-loop)
    unsigned int rec = 0;
    if (sl < m) rec = __builtin_nontemporal_load(&cv[eb + sl]);
#pragma unroll 4
    for (int j = 0; j < m; ++j) {
      unsigned int rj = __shfl(rec, j, 16);
      union { unsigned short us; _Float16 h; } vh; vh.us = (unsigned short)(rj >> 16);
      float vj = (float)vh.h;
      union { unsigned int u; half2v h; } hh;
      hh.u = hb[(size_t)(rj & 0xFFFFu) * 16];
      a0 = fmaf((float)hh.h[0], vj, a0);
      a1 = fmaf((float)hh.h[1], vj, a1);
    }
  }
  float dr = dis[row];
  union { unsigned int u; half2v h; } xc;
  xc.u = __builtin_nontemporal_load(&x0u[(size_t)slice * SLICE_D + (size_t)row * 16 + sl]);
  float r0 = fmaf(a0, dr, bvx);
  float r1 = fmaf(a1, dr, bvy);
  if (doRelu) { r0 = fmaxf(r0, 0.f); r1 = fmaxf(r1, 0.f); }
  r0 += (float)xc.h[0];
  r1 += (float)xc.h[1];
  if (outF32) {
    f32x2 o; o[0] = r0; o[1] = r1;
    __builtin_nontemporal_store(o, (f32x2*)&Houtf[(size_t)row * 128 + C0 + sl * 2]);
  } else {
    union { unsigned int u; half2v h; } ov;
    ov.h[0] = (_Float16)r0; ov.h[1] = (_Float16)r1;
    Hout16[(size_t)slice * SLICE_D + (size_t)row * 16 + sl] = ov.u;
  }

  if (doStats) {
    __shared__ float reds[512], reds2[512];   // 16 rows x 32 cols
    reds[g * 32 + sl * 2]      = r0;
    reds[g * 32 + sl * 2 + 1]  = r1;
    reds2[g * 32 + sl * 2]     = r0 * r0;
    reds2[g * 32 + sl * 2 + 1] = r1 * r1;
    __syncthreads();
    if (t < 32) {
      float ts = 0.f, ts2 = 0.f;
#pragma unroll
      for (int q = 0; q < 16; ++q) { ts += reds[q * 32 + t]; ts2 += reds2[q * 32 + t]; }
      int rep = blk & 7;
      atomicAdd(&sums[rep * 256 + C0 + t], ts);
      atomicAdd(&sums[rep * 256 + 128 + C0 + t], ts2);
    }
  }
}

// ---------------- final BN apply (derives scale/shift in-block) ----------------

__global__ __launch_bounds__(256) void k_bnapply(float* __restrict__ H,
    const float* __restrict__ sums, const float* __restrict__ gamma,
    const float* __restrict__ beta) {
  __shared__ float scl[128], shf[128];
  int t = threadIdx.x;
  if (t < 128) {
    float s = 0.f, s2 = 0.f;
#pragma unroll
    for (int r = 0; r < 8; ++r) { s += sums[r * 256 + t]; s2 += sums[r * 256 + 128 + t]; }
    float mu = s * (1.0f / N);
    float var = s2 * (1.0f / N) - mu * mu;
    float rs = rsqrtf(var + 1e-5f);
    float sc = gamma[t] * rs;
    scl[t] = sc;
    shf[t] = beta[t] - mu * sc;
  }
  __syncthreads();
  size_t i = (size_t)blockIdx.x * 256 + t;  // float4 index; total N*D/4
  float4 v = ((const float4*)H)[i];
  int c = (int)(i & 31) * 4;
  v.x = fmaf(v.x, scl[c + 0], shf[c + 0]);
  v.y = fmaf(v.y, scl[c + 1], shf[c + 1]);
  v.z = fmaf(v.z, scl[c + 2], shf[c + 2]);
  v.w = fmaf(v.w, scl[c + 3], shf[c + 3]);
  ((float4*)H)[i] = v;
}

// ---------------- launch ----------------

extern "C" void kernel_launch(void* const* d_in, const int* in_sizes, int n_in,
                              void* d_out, int out_size, void* d_ws, size_t ws_size,
                              hipStream_t stream) {
  const float* x     = (const float*)d_in[0];
  const int*   ei    = (const int*)d_in[1];
  const float* ew    = (const float*)d_in[2];
  const float* W     = (const float*)d_in[3];
  const float* b     = (const float*)d_in[4];
  const float* gamma = (const float*)d_in[5];
  const float* beta  = (const float*)d_in[6];
  float* out = (float*)d_out;

  char* ws = (char*)d_ws;
  _Float16* hlin   = (_Float16*)ws;                        // 10,240,000 B (slice-major)
  _Float16* hagg16 = (_Float16*)(ws + 10240000);           // 10,240,000 B (slice-major)
  _Float16* xh     = (_Float16*)(ws + 20480000);           // 10,240,000 B (slice-major)
  // --- contiguous zeroed region @30,720,000: 34,176 B ---
  float* sums4    = (float*)(ws + 30720000);      // 4 x 8 x 256 f32 = 32,768 B
  int*   hist     = (int*)  (ws + 30752768);      // 64 i32
  int*   histcur  = (int*)  (ws + 30753024);      // 64 i32
  int*   bktcnt   = (int*)  (ws + 30753280);      // 157 i32 (pad to 640 B)
  unsigned int* done = (unsigned int*)(ws + 30753920); // 1 u32 (pad to 256 B)
  // --- end zeroed region (30,754,176) ---
  float* dis      = (float*)(ws + 30754176);      // N f32 = 160,000
  int*   offs     = (int*)  (ws + 30914176);      // N+1 i32 (pad 160,016)
  int*   rowc     = (int*)  (ws + 31074192);      // N i32 = 160,000
  unsigned int* cv= (unsigned int*)(ws + 31234192); // (E+N) u32 = 2,720,000 B
  int*   perm     = (int*)  (ws + 33954192);      // N i32 = 160,000
  int*   bsum     = (int*)  (ws + 34114192);      // 157 i32 (pad 640)
  int*   bpre     = (int*)  (ws + 34114832);      // 157 i32 (pad 640)
  _Float16* Wt    = (_Float16*)(ws + 34115472);   // 4x128x128 fp16 = 131,072 B
  ull* binned     = (ull*)  (ws + 34246544);      // 157*5120*8 = 6,430,720 B

  // ---- one-time prep (graph-capture safe) ----
  k_zero<<<9, 256, 0, stream>>>((uint4*)sums4);
  k_bigprep<<<2913, 256, 0, stream>>>(ei, ew, x, xh, W, Wt, binned, bktcnt);
  k_bstats<<<NBKT, 256, 0, stream>>>(binned, bktcnt, dis, rowc, bsum, hist,
                                     bpre, histcur, done);

  for (int l = 0; l < 4; ++l) {
    const _Float16* xin = (l == 0) ? xh : hagg16;
    if (l == 0) {
      // layer-0 gemm (no BN) + per-bucket CSR build + degree-sort placement
      k_gemm0_fill<<<625 + NBKT + 157, 256, 0, stream>>>(xin, Wt, dis, hlin,
                                                         rowc, bpre, binned, bktcnt,
                                                         cv, offs, histcur, perm);
    } else {
      int useBN = (l == 1 || l == 2) ? 1 : 0;    // layer-3 input: layer 2 had no BN
      const float* sprev = sums4 + (size_t)(l - 1) * 2048;
      k_gemm<<<N / 64, 256, 0, stream>>>(xin, Wt + (size_t)l * 16384, sprev,
                                         gamma + (size_t)(l - 1) * D,
                                         beta + (size_t)(l - 1) * D, useBN, dis, hlin);
    }
    int doStats = (l != 2) ? 1 : 0;              // BN stats for layers 0,1,3
    int doRelu = (l < 3) ? 1 : 0;
    int outF32 = (l == 3) ? 1 : 0;               // final layer -> f32 into d_out
    k_agg<<<NSLICE * AGG_GRID, 256, 0, stream>>>((const unsigned int*)hlin, offs, cv,
                                        dis, b + (size_t)l * D,
                                        (const unsigned int*)xh, perm,
                                        doRelu, doStats, outF32,
                                        (unsigned int*)hagg16, out,
                                        sums4 + (size_t)l * 2048);
  }
  // final output = BN3(out) in place
  k_bnapply<<<(N * D / 4) / 256, 256, 0, stream>>>(out, sums4 + 3 * 2048,
                                                   gamma + 3 * D, beta + 3 * D);
}

// Round 7
// 246.529 us; speedup vs baseline: 1.3893x; 1.3893x over previous
//
#include <hip/hip_runtime.h>
#include <cstdint>
#include <cstddef>

constexpr int N = 40000;
constexpr int E = 640000;
constexpr int D = 128;
constexpr int NBKT = 157;               // dst-buckets of 256 rows each
constexpr int BCAP = 5120;              // per-bucket capacity: mean 4096, +16 sigma
constexpr int AGG_GRID = 2500;          // x16 quarters = exactly N row slots
// src-tiles for agg gather locality: 4 tiles of 10000 rows = 2.56 MB hlin each
// tile(src) = (src*6711)>>26  (exact for src in [0,40000))

typedef _Float16 half8 __attribute__((ext_vector_type(8)));
typedef float f32x4 __attribute__((ext_vector_type(4)));
typedef unsigned long long ull;

__device__ __forceinline__ unsigned int pack_rec(int idx, float v) {
  union { _Float16 h; unsigned short us; } c; c.h = (_Float16)v;
  return (unsigned int)idx | ((unsigned int)c.us << 16);
}

__device__ __forceinline__ int src_tile(int s) {
  return (int)(((unsigned)s * 6711u) >> 26);
}

// ------- zero region (contiguous): sums4 32768 | hist 256 | histcur 256 |
//         bktcnt 640 | done 256 = 34,176 B = 2136 uint4 -------

__global__ void k_zero(uint4* __restrict__ p) {
  int i = blockIdx.x * 256 + threadIdx.x;
  if (i < 2136) p[i] = make_uint4(0u, 0u, 0u, 0u);
}

// ---- fused prep: dst-bucket partition (blocks 0..156, 16 edges/thread)
//      overlapped with xconv (157..2656, row-major) and wconv (2657..2912).
//      record = src:16 | dstlocal:8 | wfix27. ----

__global__ void k_bigprep(const int* __restrict__ ei, const float* __restrict__ ew,
                          const float* __restrict__ X, _Float16* __restrict__ Xh,
                          const float* __restrict__ W, _Float16* __restrict__ Wt,
                          ull* __restrict__ binned, int* __restrict__ bktcnt) {
  int bid = blockIdx.x, t = threadIdx.x;
  if (bid < NBKT) {                       // partition: 16 edges per thread
    __shared__ int lhist[NBKT], lbase[NBKT], lrank[NBKT];
    if (t < NBKT) { lhist[t] = 0; lrank[t] = 0; }
    __syncthreads();
    int e16 = bid * 256 + t;
    bool act = (e16 < E / 16);            // E/16 = 40000
    int4 s4[4], d4[4]; float4 w4[4];
    if (act) {
#pragma unroll
      for (int u = 0; u < 4; ++u) {
        s4[u] = ((const int4*)ei)[e16 * 4 + u];
        d4[u] = ((const int4*)(ei + E))[e16 * 4 + u];
        w4[u] = ((const float4*)ew)[e16 * 4 + u];
      }
#pragma unroll
      for (int u = 0; u < 4; ++u) {
        atomicAdd(&lhist[d4[u].x >> 8], 1); atomicAdd(&lhist[d4[u].y >> 8], 1);
        atomicAdd(&lhist[d4[u].z >> 8], 1); atomicAdd(&lhist[d4[u].w >> 8], 1);
      }
    }
    __syncthreads();
    if (t < NBKT && lhist[t] > 0) lbase[t] = atomicAdd(&bktcnt[t], lhist[t]);
    __syncthreads();
    if (act) {
      auto emit = [&](int s, int dcol, float w) {
        int bkt = dcol >> 8;
        int rank = atomicAdd(&lrank[bkt], 1);
        int pos = lbase[bkt] + rank;
        ull rec = (ull)(unsigned)(s & 0xFFFF)
                | ((ull)(unsigned)(dcol & 255) << 16)
                | ((ull)__float2uint_rn(w * 67108864.0f) << 24);   // wfix27
        if (pos < BCAP) binned[(size_t)bkt * BCAP + pos] = rec;
      };
#pragma unroll
      for (int u = 0; u < 4; ++u) {
        emit(s4[u].x, d4[u].x, w4[u].x); emit(s4[u].y, d4[u].y, w4[u].y);
        emit(s4[u].z, d4[u].z, w4[u].z); emit(s4[u].w, d4[u].w, w4[u].w);
      }
    }
  } else if (bid < 2657) {                // X -> fp16, 8 elems/thread, row-major
    int i = (bid - NBKT) * 256 + t;       // < 640,000
    float4 v0 = ((const float4*)X)[i * 2];
    float4 v1 = ((const float4*)X)[i * 2 + 1];
    half8 h;
    h[0] = (_Float16)v0.x; h[1] = (_Float16)v0.y; h[2] = (_Float16)v0.z; h[3] = (_Float16)v0.w;
    h[4] = (_Float16)v1.x; h[5] = (_Float16)v1.y; h[6] = (_Float16)v1.z; h[7] = (_Float16)v1.w;
    ((half8*)Xh)[i] = h;
  } else {                                // W transpose+convert: Wt[l][c][k] = W[l][k][c]
    int o = (bid - 2657) * 256 + t;       // < 65,536
    int l = o >> 14, rem = o & 16383, c = rem >> 7, k = rem & 127;
    Wt[o] = (_Float16)W[l * 16384 + k * 128 + c];
  }
}

// ---- per-bucket stats: degree (LDS u64 atomics) + per-row SRC-TILE counts
//      (4x16-bit fields in u64) + LAST-BLOCK FINALIZE (bsum scan + hist
//      suffix-scan). ----

__global__ __launch_bounds__(256) void k_bstats(const ull* __restrict__ binned,
    const int* __restrict__ bktcnt, float* __restrict__ dis, int* __restrict__ rowc,
    ull* __restrict__ tilecnt,
    int* __restrict__ bsum, int* __restrict__ hist, int* __restrict__ bpre,
    int* __restrict__ histcur, unsigned int* __restrict__ done) {
  __shared__ ull acc[256];
  __shared__ ull cnt4[256];
  __shared__ int lhist[64];
  __shared__ int red[256];
  __shared__ int amlast;
  int bkt = blockIdx.x, t = threadIdx.x;
  acc[t] = 0ULL;
  cnt4[t] = 0ULL;
  if (t < 64) lhist[t] = 0;
  __syncthreads();
  int cnt = min(bktcnt[bkt], BCAP);
  const ull* bp = binned + (size_t)bkt * BCAP;
  for (int e = t; e < cnt; e += 256) {
    ull r = bp[e];
    int local = (int)((r >> 16) & 255);
    int src = (int)(r & 0xFFFFu);
    atomicAdd(&acc[local], (1ULL << 40) | (r >> 24));   // count | wfix sum
    atomicAdd(&cnt4[local], 1ULL << (16 * src_tile(src)));
  }
  __syncthreads();
  int row = bkt * 256 + t;
  int c = 0;
  if (row < N) {
    ull a = acc[t];
    c = (int)(a >> 40) + 1;                             // +1: self-loop
    float deg = (float)(a & ((1ULL << 40) - 1)) * (1.0f / 67108864.0f);
    dis[row] = rsqrtf(deg + 1.0f);                      // +1 = self-loop weight
    rowc[row] = c;
    tilecnt[row] = cnt4[t] + (1ULL << (16 * src_tile(row)));  // self in its tile
    atomicAdd(&lhist[min(c, 63)], 1);
  }
  red[t] = c;
  __syncthreads();
  for (int off = 128; off > 0; off >>= 1) {
    if (t < off) red[t] += red[t + off];
    __syncthreads();
  }
  if (t == 0) bsum[bkt] = red[0];
  if (t < 64 && lhist[t] > 0) atomicAdd(&hist[t], lhist[t]);
  __syncthreads();
  if (t == 0) {
    __threadfence();
    amlast = (atomicAdd(done, 1u) == NBKT - 1);
  }
  __syncthreads();
  if (!amlast) return;
  __threadfence();
  red[t] = (t < NBKT) ? bsum[t] : 0;
  __syncthreads();
  for (int off = 1; off < 256; off <<= 1) {
    int v = red[t];
    int add = (t >= off) ? red[t - off] : 0;
    __syncthreads();
    red[t] = v + add;
    __syncthreads();
  }
  if (t < NBKT) bpre[t] = (t == 0) ? 0 : red[t - 1];
  if (t < 64) {
    int s = 0;
    for (int b2 = t + 1; b2 < 64; ++b2) s += hist[b2];
    histcur[t] = s;
  }
}

// ------- GEMM body (MFMA fp16; BN+cvt on A load; row-major) -------

__device__ __forceinline__ void gemm_body(int bid, int tid, const _Float16* __restrict__ X,
    const _Float16* __restrict__ Wt, const float* __restrict__ sums,
    const float* __restrict__ gamma, const float* __restrict__ beta, int useBN,
    const float* __restrict__ dis, _Float16* __restrict__ Hout,
    float* scl, float* shf) {
  if (tid < 128) {
    if (useBN) {   // derive BN scale/shift from replicated sums (2 KB, L2-hot)
      float s = 0.f, s2 = 0.f;
#pragma unroll
      for (int r = 0; r < 8; ++r) { s += sums[r * 256 + tid]; s2 += sums[r * 256 + 128 + tid]; }
      float mu = s * (1.0f / N);
      float var = s2 * (1.0f / N) - mu * mu;
      float rs = rsqrtf(var + 1e-5f);
      float sc = gamma[tid] * rs;
      scl[tid] = sc;
      shf[tid] = beta[tid] - mu * sc;
    } else {
      scl[tid] = 1.0f;
      shf[tid] = 0.0f;
    }
  }
  __syncthreads();

  int wv = tid >> 6, lane = tid & 63;
  int fr = lane & 15, kg = lane >> 4;
  int arow = bid * 64 + wv * 16 + fr;
  const _Float16* xrow = X + (size_t)arow * D;

  half8 af[4];
#pragma unroll
  for (int kc = 0; kc < 4; ++kc) {
    int k0 = kc * 32 + kg * 8;
    half8 xr = *(const half8*)&xrow[k0];
    half8 a;
#pragma unroll
    for (int u = 0; u < 8; ++u)
      a[u] = (_Float16)fmaf((float)xr[u], scl[k0 + u], shf[k0 + u]);
    af[kc] = a;
  }

  f32x4 acc[8];
#pragma unroll
  for (int ct = 0; ct < 8; ++ct) acc[ct] = (f32x4){0.f, 0.f, 0.f, 0.f};

#pragma unroll
  for (int ct = 0; ct < 8; ++ct) {
    const _Float16* wcol = Wt + (size_t)(ct * 16 + fr) * 128;
#pragma unroll
    for (int kc = 0; kc < 4; ++kc) {
      half8 bf = *(const half8*)&wcol[kc * 32 + kg * 8];
      acc[ct] = __builtin_amdgcn_mfma_f32_16x16x32_f16(af[kc], bf, acc[ct], 0, 0, 0);
    }
  }

  int orow0 = bid * 64 + wv * 16 + kg * 4;
#pragma unroll
  for (int rg = 0; rg < 4; ++rg) {
    int grow = orow0 + rg;
    float dsv = dis[grow];                 // pre-scale by dis[src] for the gather
    _Float16* hrow = Hout + (size_t)grow * D;
#pragma unroll
    for (int ct = 0; ct < 8; ++ct)
      hrow[ct * 16 + fr] = (_Float16)(acc[ct][rg] * dsv);
  }
}

__global__ __launch_bounds__(256) void k_gemm(const _Float16* __restrict__ X,
    const _Float16* __restrict__ Wt, const float* __restrict__ sums,
    const float* __restrict__ gamma, const float* __restrict__ beta, int useBN,
    const float* __restrict__ dis, _Float16* __restrict__ Hout) {
  __shared__ float scl[128], shf[128];
  gemm_body(blockIdx.x, threadIdx.x, X, Wt, sums, gamma, beta, useBN, dis, Hout, scl, shf);
}

// ---- layer-0 gemm + per-bucket CSR build (TILE-ORDERED within each row) +
//      degree-sort placement ----
// Fill: 4 cursors per row (LDS lcur[256*4]); cv within a row is ordered by
// src-tile so k_agg can walk tile segments. Self-loop placed in its own tile.

__global__ __launch_bounds__(256) void k_gemm0_fill(const _Float16* __restrict__ X,
    const _Float16* __restrict__ Wt, const float* __restrict__ dis,
    _Float16* __restrict__ Hout,
    const int* __restrict__ rowc, const ull* __restrict__ tilecnt,
    const int* __restrict__ bpre,
    const ull* __restrict__ binned, const int* __restrict__ bktcnt,
    unsigned int* __restrict__ cv, int* __restrict__ offs,
    int* __restrict__ histcur, int* __restrict__ perm) {
  int bid = blockIdx.x, t = threadIdx.x;
  if (bid < 625) {
    __shared__ float scl[128], shf[128];
    gemm_body(bid, t, X, Wt, (const float*)nullptr, (const float*)nullptr,
              (const float*)nullptr, 0, dis, Hout, scl, shf);
  } else if (bid < 625 + NBKT) {
    int bkt = bid - 625;
    __shared__ int lcur[256 * 4];
    __shared__ int s[256];
    int row = bkt * 256 + t;
    int c = (row < N) ? rowc[row] : 0;
    s[t] = c;
    __syncthreads();
    for (int off = 1; off < 256; off <<= 1) {
      int v = s[t];
      int add = (t >= off) ? s[t - off] : 0;
      __syncthreads();
      s[t] = v + add;
      __syncthreads();
    }
    int run = bpre[bkt] + s[t] - c;        // exclusive prefix (row's cv base)
    if (row < N) {
      offs[row] = run;
      ull tc = tilecnt[row];
      int b0 = run;
      int b1 = b0 + (int)(tc & 0xFFFF);
      int b2 = b1 + (int)((tc >> 16) & 0xFFFF);
      int b3 = b2 + (int)((tc >> 32) & 0xFFFF);
      lcur[t * 4 + 0] = b0; lcur[t * 4 + 1] = b1;
      lcur[t * 4 + 2] = b2; lcur[t * 4 + 3] = b3;
      int ts = src_tile(row);              // self-loop -> its own tile segment
      int slot = lcur[t * 4 + ts];
      cv[slot] = pack_rec(row, 1.0f);
      lcur[t * 4 + ts] = slot + 1;         // pre-barrier, no race
    } else {
#pragma unroll
      for (int k = 0; k < 4; ++k) lcur[t * 4 + k] = 0;
    }
    if (row == N - 1) offs[N] = N + E;
    __syncthreads();
    int cnt = min(bktcnt[bkt], BCAP);
    const ull* bp = binned + (size_t)bkt * BCAP;
    for (int e = t; e < cnt; e += 256) {
      ull r = bp[e];
      int local = (int)((r >> 16) & 255);
      int srcv = (int)(r & 0xFFFFu);
      float w = (float)(unsigned)(r >> 24) * (1.0f / 67108864.0f);
      int slot = atomicAdd(&lcur[local * 4 + src_tile(srcv)], 1);
      cv[slot] = pack_rec(srcv, w);
    }
  } else {
    __shared__ int lhist[64], lbase[64];
    if (t < 64) lhist[t] = 0;
    __syncthreads();
    int i = (bid - (625 + NBKT)) * 256 + t;
    bool valid = (i < N);
    int bin = 0, myrank = 0;
    if (valid) {
      int c = rowc[i];
      bin = min(c, 63);
      myrank = atomicAdd(&lhist[bin], 1);
    }
    __syncthreads();
    if (t < 64 && lhist[t] > 0) lbase[t] = atomicAdd(&histcur[t], lhist[t]);
    __syncthreads();
    if (valid) perm[lbase[bin] + myrank] = i;
  }
}

// ---- Aggregation + skip + (optional) fused BN stats — SRC-TILE PHASED ----
// QUARTER-WAVE-PER-ROW. Each row's cv is tile-ordered; all blocks walk tiles
// 0->3 in the same order, so the co-resident blocks keep the active 2.56 MB
// hlin tile L2-resident per XCD (fits 4 MB). Per-edge work identical to the
// untiled version — only intra-row summation order changes (cursor order was
// already arbitrary).

__global__ __launch_bounds__(256) void k_agg(const uint4* __restrict__ Hu4,
    const int* __restrict__ offs, const ull* __restrict__ tilecnt,
    const unsigned int* __restrict__ cv,
    const float* __restrict__ dis, const float* __restrict__ bias,
    const uint4* __restrict__ x0h, const int* __restrict__ perm,
    int doRelu, int doStats, int outF32,
    _Float16* __restrict__ Hout16, float* __restrict__ Houtf, float* __restrict__ sums) {
  int t = threadIdx.x;
  int sl = t & 15;                       // lane within quarter
  int g = t >> 4;                        // quarter id 0..15
  int row = perm[blockIdx.x * 16 + g];   // degree-sorted row for this quarter
  float4 bv0 = ((const float4*)bias)[sl * 2];
  float4 bv1 = ((const float4*)bias)[sl * 2 + 1];
  const uint4* hp = Hu4 + sl;

  ull tc = tilecnt[row];
  int e = offs[row];
  float a[8];
#pragma unroll
  for (int k = 0; k < 8; ++k) a[k] = 0.f;
#pragma unroll 1
  for (int tile = 0; tile < 4; ++tile) {
    int cnt = (int)((tc >> (16 * tile)) & 0xFFFF);
    int eend = e + cnt;
    for (int eb = e; eb < eend; eb += 16) {
      int m = min(16, eend - eb);
      unsigned int rec = 0;
      if (sl < m) rec = cv[eb + sl];
#pragma unroll 8
      for (int j = 0; j < m; ++j) {
        unsigned int rj = __shfl(rec, j, 16);
        int sj = (int)(rj & 0xFFFFu);
        union { unsigned short us; _Float16 h; } vh; vh.us = (unsigned short)(rj >> 16);
        float vj = (float)vh.h;
        union { uint4 u; _Float16 hh[8]; } cu;
        cu.u = hp[(size_t)sj * 16];
#pragma unroll
        for (int k = 0; k < 8; ++k) a[k] = fmaf((float)cu.hh[k], vj, a[k]);
      }
    }
    e = eend;
  }
  float dr = dis[row];
  union { uint4 u; _Float16 hh[8]; } xc;
  xc.u = x0h[(size_t)row * 16 + sl];
  float rr[8];
  rr[0] = fmaf(a[0], dr, bv0.x); rr[1] = fmaf(a[1], dr, bv0.y);
  rr[2] = fmaf(a[2], dr, bv0.z); rr[3] = fmaf(a[3], dr, bv0.w);
  rr[4] = fmaf(a[4], dr, bv1.x); rr[5] = fmaf(a[5], dr, bv1.y);
  rr[6] = fmaf(a[6], dr, bv1.z); rr[7] = fmaf(a[7], dr, bv1.w);
  if (doRelu) {
#pragma unroll
    for (int k = 0; k < 8; ++k) rr[k] = fmaxf(rr[k], 0.f);
  }
#pragma unroll
  for (int k = 0; k < 8; ++k) rr[k] += (float)xc.hh[k];
  if (outF32) {
    float4 o0, o1;
    o0.x = rr[0]; o0.y = rr[1]; o0.z = rr[2]; o0.w = rr[3];
    o1.x = rr[4]; o1.y = rr[5]; o1.z = rr[6]; o1.w = rr[7];
    ((float4*)Houtf)[(size_t)row * 32 + sl * 2] = o0;
    ((float4*)Houtf)[(size_t)row * 32 + sl * 2 + 1] = o1;
  } else {
    union { uint4 u; _Float16 hh[8]; } ov;
#pragma unroll
    for (int k = 0; k < 8; ++k) ov.hh[k] = (_Float16)rr[k];
    ((uint4*)Hout16)[(size_t)row * 16 + sl] = ov.u;
  }

  if (doStats) {
    __shared__ float reds[16 * 128], reds2[16 * 128];   // 8 KB + 8 KB
#pragma unroll
    for (int k = 0; k < 8; ++k) {
      reds[g * 128 + sl * 8 + k] = rr[k];
      reds2[g * 128 + sl * 8 + k] = rr[k] * rr[k];
    }
    __syncthreads();
    if (t < 128) {
      float ts = 0.f, ts2 = 0.f;
#pragma unroll
      for (int j2 = 0; j2 < 16; ++j2) { ts += reds[j2 * 128 + t]; ts2 += reds2[j2 * 128 + t]; }
      int rep = blockIdx.x & 7;
      atomicAdd(&sums[rep * 256 + t], ts);
      atomicAdd(&sums[rep * 256 + 128 + t], ts2);
    }
  }
}

// ---------------- final BN apply (derives scale/shift in-block) ----------------

__global__ __launch_bounds__(256) void k_bnapply(float* __restrict__ H,
    const float* __restrict__ sums, const float* __restrict__ gamma,
    const float* __restrict__ beta) {
  __shared__ float scl[128], shf[128];
  int t = threadIdx.x;
  if (t < 128) {
    float s = 0.f, s2 = 0.f;
#pragma unroll
    for (int r = 0; r < 8; ++r) { s += sums[r * 256 + t]; s2 += sums[r * 256 + 128 + t]; }
    float mu = s * (1.0f / N);
    float var = s2 * (1.0f / N) - mu * mu;
    float rs = rsqrtf(var + 1e-5f);
    float sc = gamma[t] * rs;
    scl[t] = sc;
    shf[t] = beta[t] - mu * sc;
  }
  __syncthreads();
  size_t i = (size_t)blockIdx.x * 256 + t;  // float4 index; total N*D/4
  float4 v = ((const float4*)H)[i];
  int c = (int)(i & 31) * 4;
  v.x = fmaf(v.x, scl[c + 0], shf[c + 0]);
  v.y = fmaf(v.y, scl[c + 1], shf[c + 1]);
  v.z = fmaf(v.z, scl[c + 2], shf[c + 2]);
  v.w = fmaf(v.w, scl[c + 3], shf[c + 3]);
  ((float4*)H)[i] = v;
}

// ---------------- launch ----------------

extern "C" void kernel_launch(void* const* d_in, const int* in_sizes, int n_in,
                              void* d_out, int out_size, void* d_ws, size_t ws_size,
                              hipStream_t stream) {
  const float* x     = (const float*)d_in[0];
  const int*   ei    = (const int*)d_in[1];
  const float* ew    = (const float*)d_in[2];
  const float* W     = (const float*)d_in[3];
  const float* b     = (const float*)d_in[4];
  const float* gamma = (const float*)d_in[5];
  const float* beta  = (const float*)d_in[6];
  float* out = (float*)d_out;

  char* ws = (char*)d_ws;
  _Float16* hlin   = (_Float16*)ws;                        // 10,240,000 B
  _Float16* hagg16 = (_Float16*)(ws + 10240000);           // 10,240,000 B
  _Float16* xh     = (_Float16*)(ws + 20480000);           // 10,240,000 B
  // --- contiguous zeroed region @30,720,000: 34,176 B ---
  float* sums4    = (float*)(ws + 30720000);      // 4 x 8 x 256 f32 = 32,768 B
  int*   hist     = (int*)  (ws + 30752768);      // 64 i32
  int*   histcur  = (int*)  (ws + 30753024);      // 64 i32
  int*   bktcnt   = (int*)  (ws + 30753280);      // 157 i32 (pad to 640 B)
  unsigned int* done = (unsigned int*)(ws + 30753920); // 1 u32 (pad to 256 B)
  // --- end zeroed region (30,754,176) ---
  float* dis      = (float*)(ws + 30754176);      // N f32 = 160,000
  int*   offs     = (int*)  (ws + 30914176);      // N+1 i32 (pad 160,016)
  int*   rowc     = (int*)  (ws + 31074192);      // N i32 = 160,000
  unsigned int* cv= (unsigned int*)(ws + 31234192); // (E+N) u32 = 2,720,000 B
  int*   perm     = (int*)  (ws + 33954192);      // N i32 = 160,000
  int*   bsum     = (int*)  (ws + 34114192);      // 157 i32 (pad 640)
  int*   bpre     = (int*)  (ws + 34114832);      // 157 i32 (pad 640)
  _Float16* Wt    = (_Float16*)(ws + 34115472);   // 4x128x128 fp16 = 131,072 B
  ull* binned     = (ull*)  (ws + 34246544);      // 157*5120*8 = 6,430,720 B
  ull* tilecnt    = (ull*)  (ws + 40677264);      // N u64 = 320,000 B

  // ---- one-time prep (graph-capture safe) ----
  k_zero<<<9, 256, 0, stream>>>((uint4*)sums4);
  k_bigprep<<<2913, 256, 0, stream>>>(ei, ew, x, xh, W, Wt, binned, bktcnt);
  k_bstats<<<NBKT, 256, 0, stream>>>(binned, bktcnt, dis, rowc, tilecnt,
                                     bsum, hist, bpre, histcur, done);

  for (int l = 0; l < 4; ++l) {
    const _Float16* xin = (l == 0) ? xh : hagg16;
    if (l == 0) {
      // layer-0 gemm (no BN) + tile-ordered CSR build + degree-sort placement
      k_gemm0_fill<<<625 + NBKT + 157, 256, 0, stream>>>(xin, Wt, dis, hlin,
                                                         rowc, tilecnt, bpre,
                                                         binned, bktcnt,
                                                         cv, offs, histcur, perm);
    } else {
      int useBN = (l == 1 || l == 2) ? 1 : 0;    // layer-3 input: layer 2 had no BN
      const float* sprev = sums4 + (size_t)(l - 1) * 2048;
      k_gemm<<<N / 64, 256, 0, stream>>>(xin, Wt + (size_t)l * 16384, sprev,
                                         gamma + (size_t)(l - 1) * D,
                                         beta + (size_t)(l - 1) * D, useBN, dis, hlin);
    }
    int doStats = (l != 2) ? 1 : 0;              // BN stats for layers 0,1,3
    int doRelu = (l < 3) ? 1 : 0;
    int outF32 = (l == 3) ? 1 : 0;               // final layer -> f32 into d_out
    k_agg<<<AGG_GRID, 256, 0, stream>>>((const uint4*)hlin, offs, tilecnt, cv, dis,
                                        b + (size_t)l * D, (const uint4*)xh, perm,
                                        doRelu, doStats, outF32, hagg16, out,
                                        sums4 + (size_t)l * 2048);
  }
  // final output = BN3(out) in place
  k_bnapply<<<(N * D / 4) / 256, 256, 0, stream>>>(out, sums4 + 3 * 2048,
                                                   gamma + 3 * D, beta + 3 * D);
}

// Round 8
// 220.778 us; speedup vs baseline: 1.5513x; 1.1166x over previous
//
#include <hip/hip_runtime.h>
#include <cstdint>
#include <cstddef>

constexpr int N = 40000;
constexpr int E = 640000;
constexpr int D = 128;
constexpr int NBKT = 157;               // dst-buckets of 256 rows each
constexpr int BCAP = 5120;              // per-bucket capacity: mean 4096, +16 sigma
constexpr int AGG_GRID = 2500;          // x16 quarters = exactly N row slots
// 8 src-tiles of 5000 rows (1.28 MB hlin each) for agg gather phase-locality.
// tile(src) = (src*13422)>>26, exact for src in [0,40000).

typedef _Float16 half8 __attribute__((ext_vector_type(8)));
typedef float f32x4 __attribute__((ext_vector_type(4)));
typedef unsigned long long ull;

__device__ __forceinline__ unsigned int pack_rec(int idx, float v) {
  union { _Float16 h; unsigned short us; } c; c.h = (_Float16)v;
  return (unsigned int)idx | ((unsigned int)c.us << 16);
}

__device__ __forceinline__ int src_tile(int s) {
  return (int)(((unsigned)s * 13422u) >> 26);
}

// ------- zero region (contiguous): sums4 32768 | hist 256 | histcur 256 |
//         bktcnt 640 | done 256 = 34,176 B = 2136 uint4 -------

__global__ void k_zero(uint4* __restrict__ p) {
  int i = blockIdx.x * 256 + threadIdx.x;
  if (i < 2136) p[i] = make_uint4(0u, 0u, 0u, 0u);
}

// ---- fused prep: dst-bucket partition (blocks 0..156, 16 edges/thread)
//      overlapped with xconv (157..2656, row-major) and wconv (2657..2912).
//      record = src:16 | dstlocal:8 | wfix27. ----

__global__ void k_bigprep(const int* __restrict__ ei, const float* __restrict__ ew,
                          const float* __restrict__ X, _Float16* __restrict__ Xh,
                          const float* __restrict__ W, _Float16* __restrict__ Wt,
                          ull* __restrict__ binned, int* __restrict__ bktcnt) {
  int bid = blockIdx.x, t = threadIdx.x;
  if (bid < NBKT) {                       // partition: 16 edges per thread
    __shared__ int lhist[NBKT], lbase[NBKT], lrank[NBKT];
    if (t < NBKT) { lhist[t] = 0; lrank[t] = 0; }
    __syncthreads();
    int e16 = bid * 256 + t;
    bool act = (e16 < E / 16);            // E/16 = 40000
    int4 s4[4], d4[4]; float4 w4[4];
    if (act) {
#pragma unroll
      for (int u = 0; u < 4; ++u) {
        s4[u] = ((const int4*)ei)[e16 * 4 + u];
        d4[u] = ((const int4*)(ei + E))[e16 * 4 + u];
        w4[u] = ((const float4*)ew)[e16 * 4 + u];
      }
#pragma unroll
      for (int u = 0; u < 4; ++u) {
        atomicAdd(&lhist[d4[u].x >> 8], 1); atomicAdd(&lhist[d4[u].y >> 8], 1);
        atomicAdd(&lhist[d4[u].z >> 8], 1); atomicAdd(&lhist[d4[u].w >> 8], 1);
      }
    }
    __syncthreads();
    if (t < NBKT && lhist[t] > 0) lbase[t] = atomicAdd(&bktcnt[t], lhist[t]);
    __syncthreads();
    if (act) {
      auto emit = [&](int s, int dcol, float w) {
        int bkt = dcol >> 8;
        int rank = atomicAdd(&lrank[bkt], 1);
        int pos = lbase[bkt] + rank;
        ull rec = (ull)(unsigned)(s & 0xFFFF)
                | ((ull)(unsigned)(dcol & 255) << 16)
                | ((ull)__float2uint_rn(w * 67108864.0f) << 24);   // wfix27
        if (pos < BCAP) binned[(size_t)bkt * BCAP + pos] = rec;
      };
#pragma unroll
      for (int u = 0; u < 4; ++u) {
        emit(s4[u].x, d4[u].x, w4[u].x); emit(s4[u].y, d4[u].y, w4[u].y);
        emit(s4[u].z, d4[u].z, w4[u].z); emit(s4[u].w, d4[u].w, w4[u].w);
      }
    }
  } else if (bid < 2657) {                // X -> fp16, 8 elems/thread, row-major
    int i = (bid - NBKT) * 256 + t;       // < 640,000
    float4 v0 = ((const float4*)X)[i * 2];
    float4 v1 = ((const float4*)X)[i * 2 + 1];
    half8 h;
    h[0] = (_Float16)v0.x; h[1] = (_Float16)v0.y; h[2] = (_Float16)v0.z; h[3] = (_Float16)v0.w;
    h[4] = (_Float16)v1.x; h[5] = (_Float16)v1.y; h[6] = (_Float16)v1.z; h[7] = (_Float16)v1.w;
    ((half8*)Xh)[i] = h;
  } else {                                // W transpose+convert: Wt[l][c][k] = W[l][k][c]
    int o = (bid - 2657) * 256 + t;       // < 65,536
    int l = o >> 14, rem = o & 16383, c = rem >> 7, k = rem & 127;
    Wt[o] = (_Float16)W[l * 16384 + k * 128 + c];
  }
}

// ---- per-bucket stats: degree (LDS u64 atomics) + per-row 8x8-bit SRC-TILE
//      counts + LAST-BLOCK FINALIZE (bsum scan + hist suffix-scan). ----

__global__ __launch_bounds__(256) void k_bstats(const ull* __restrict__ binned,
    const int* __restrict__ bktcnt, float* __restrict__ dis, int* __restrict__ rowc,
    ull* __restrict__ tilecnt,
    int* __restrict__ bsum, int* __restrict__ hist, int* __restrict__ bpre,
    int* __restrict__ histcur, unsigned int* __restrict__ done) {
  __shared__ ull acc[256];
  __shared__ ull cnt8[256];
  __shared__ int lhist[64];
  __shared__ int red[256];
  __shared__ int amlast;
  int bkt = blockIdx.x, t = threadIdx.x;
  acc[t] = 0ULL;
  cnt8[t] = 0ULL;
  if (t < 64) lhist[t] = 0;
  __syncthreads();
  int cnt = min(bktcnt[bkt], BCAP);
  const ull* bp = binned + (size_t)bkt * BCAP;
  for (int e = t; e < cnt; e += 256) {
    ull r = bp[e];
    int local = (int)((r >> 16) & 255);
    int src = (int)(r & 0xFFFFu);
    atomicAdd(&acc[local], (1ULL << 40) | (r >> 24));   // count | wfix sum
    atomicAdd(&cnt8[local], 1ULL << (8 * src_tile(src)));
  }
  __syncthreads();
  int row = bkt * 256 + t;
  int c = 0;
  if (row < N) {
    ull a = acc[t];
    c = (int)(a >> 40) + 1;                             // +1: self-loop
    float deg = (float)(a & ((1ULL << 40) - 1)) * (1.0f / 67108864.0f);
    dis[row] = rsqrtf(deg + 1.0f);                      // +1 = self-loop weight
    rowc[row] = c;
    tilecnt[row] = cnt8[t] + (1ULL << (8 * src_tile(row)));  // self in its tile
    atomicAdd(&lhist[min(c, 63)], 1);
  }
  red[t] = c;
  __syncthreads();
  for (int off = 128; off > 0; off >>= 1) {
    if (t < off) red[t] += red[t + off];
    __syncthreads();
  }
  if (t == 0) bsum[bkt] = red[0];
  if (t < 64 && lhist[t] > 0) atomicAdd(&hist[t], lhist[t]);
  __syncthreads();
  if (t == 0) {
    __threadfence();
    amlast = (atomicAdd(done, 1u) == NBKT - 1);
  }
  __syncthreads();
  if (!amlast) return;
  __threadfence();
  red[t] = (t < NBKT) ? bsum[t] : 0;
  __syncthreads();
  for (int off = 1; off < 256; off <<= 1) {
    int v = red[t];
    int add = (t >= off) ? red[t - off] : 0;
    __syncthreads();
    red[t] = v + add;
    __syncthreads();
  }
  if (t < NBKT) bpre[t] = (t == 0) ? 0 : red[t - 1];
  if (t < 64) {
    int s = 0;
    for (int b2 = t + 1; b2 < 64; ++b2) s += hist[b2];
    histcur[t] = s;
  }
}

// ------- GEMM body (MFMA fp16; BN+cvt on A load; row-major) -------

__device__ __forceinline__ void gemm_body(int bid, int tid, const _Float16* __restrict__ X,
    const _Float16* __restrict__ Wt, const float* __restrict__ sums,
    const float* __restrict__ gamma, const float* __restrict__ beta, int useBN,
    const float* __restrict__ dis, _Float16* __restrict__ Hout,
    float* scl, float* shf) {
  if (tid < 128) {
    if (useBN) {   // derive BN scale/shift from replicated sums (2 KB, L2-hot)
      float s = 0.f, s2 = 0.f;
#pragma unroll
      for (int r = 0; r < 8; ++r) { s += sums[r * 256 + tid]; s2 += sums[r * 256 + 128 + tid]; }
      float mu = s * (1.0f / N);
      float var = s2 * (1.0f / N) - mu * mu;
      float rs = rsqrtf(var + 1e-5f);
      float sc = gamma[tid] * rs;
      scl[tid] = sc;
      shf[tid] = beta[tid] - mu * sc;
    } else {
      scl[tid] = 1.0f;
      shf[tid] = 0.0f;
    }
  }
  __syncthreads();

  int wv = tid >> 6, lane = tid & 63;
  int fr = lane & 15, kg = lane >> 4;
  int arow = bid * 64 + wv * 16 + fr;
  const _Float16* xrow = X + (size_t)arow * D;

  half8 af[4];
#pragma unroll
  for (int kc = 0; kc < 4; ++kc) {
    int k0 = kc * 32 + kg * 8;
    half8 xr = *(const half8*)&xrow[k0];
    half8 a;
#pragma unroll
    for (int u = 0; u < 8; ++u)
      a[u] = (_Float16)fmaf((float)xr[u], scl[k0 + u], shf[k0 + u]);
    af[kc] = a;
  }

  f32x4 acc[8];
#pragma unroll
  for (int ct = 0; ct < 8; ++ct) acc[ct] = (f32x4){0.f, 0.f, 0.f, 0.f};

#pragma unroll
  for (int ct = 0; ct < 8; ++ct) {
    const _Float16* wcol = Wt + (size_t)(ct * 16 + fr) * 128;
#pragma unroll
    for (int kc = 0; kc < 4; ++kc) {
      half8 bf = *(const half8*)&wcol[kc * 32 + kg * 8];
      acc[ct] = __builtin_amdgcn_mfma_f32_16x16x32_f16(af[kc], bf, acc[ct], 0, 0, 0);
    }
  }

  int orow0 = bid * 64 + wv * 16 + kg * 4;
#pragma unroll
  for (int rg = 0; rg < 4; ++rg) {
    int grow = orow0 + rg;
    float dsv = dis[grow];                 // pre-scale by dis[src] for the gather
    _Float16* hrow = Hout + (size_t)grow * D;
#pragma unroll
    for (int ct = 0; ct < 8; ++ct)
      hrow[ct * 16 + fr] = (_Float16)(acc[ct][rg] * dsv);
  }
}

__global__ __launch_bounds__(256) void k_gemm(const _Float16* __restrict__ X,
    const _Float16* __restrict__ Wt, const float* __restrict__ sums,
    const float* __restrict__ gamma, const float* __restrict__ beta, int useBN,
    const float* __restrict__ dis, _Float16* __restrict__ Hout) {
  __shared__ float scl[128], shf[128];
  gemm_body(blockIdx.x, threadIdx.x, X, Wt, sums, gamma, beta, useBN, dis, Hout, scl, shf);
}

// ---- layer-0 gemm + per-bucket CSR build (8-tile-ordered within each row) +
//      degree-sort placement ----
// Fill: 8 cursors per row (LDS lcur[256*8]); cv within a row is ordered by
// src-tile. The agg kernel walks [e0,e1) linearly — tile order is purely a
// data-layout property (R7's explicit segment loop was pure overhead).

__global__ __launch_bounds__(256) void k_gemm0_fill(const _Float16* __restrict__ X,
    const _Float16* __restrict__ Wt, const float* __restrict__ dis,
    _Float16* __restrict__ Hout,
    const int* __restrict__ rowc, const ull* __restrict__ tilecnt,
    const int* __restrict__ bpre,
    const ull* __restrict__ binned, const int* __restrict__ bktcnt,
    unsigned int* __restrict__ cv, int* __restrict__ offs,
    int* __restrict__ histcur, int* __restrict__ perm) {
  int bid = blockIdx.x, t = threadIdx.x;
  if (bid < 625) {
    __shared__ float scl[128], shf[128];
    gemm_body(bid, t, X, Wt, (const float*)nullptr, (const float*)nullptr,
              (const float*)nullptr, 0, dis, Hout, scl, shf);
  } else if (bid < 625 + NBKT) {
    int bkt = bid - 625;
    __shared__ int lcur[256 * 8];
    __shared__ int s[256];
    int row = bkt * 256 + t;
    int c = (row < N) ? rowc[row] : 0;
    s[t] = c;
    __syncthreads();
    for (int off = 1; off < 256; off <<= 1) {
      int v = s[t];
      int add = (t >= off) ? s[t - off] : 0;
      __syncthreads();
      s[t] = v + add;
      __syncthreads();
    }
    int run = bpre[bkt] + s[t] - c;        // exclusive prefix (row's cv base)
    if (row < N) {
      offs[row] = run;
      ull tc = tilecnt[row];
      int base = run;
#pragma unroll
      for (int k = 0; k < 8; ++k) {
        lcur[t * 8 + k] = base;
        base += (int)((tc >> (8 * k)) & 0xFF);
      }
      int ts = src_tile(row);              // self-loop -> its own tile segment
      int slot = lcur[t * 8 + ts];
      cv[slot] = pack_rec(row, 1.0f);
      lcur[t * 8 + ts] = slot + 1;         // pre-barrier, no race
    } else {
#pragma unroll
      for (int k = 0; k < 8; ++k) lcur[t * 8 + k] = 0;
    }
    if (row == N - 1) offs[N] = N + E;
    __syncthreads();
    int cnt = min(bktcnt[bkt], BCAP);
    const ull* bp = binned + (size_t)bkt * BCAP;
    for (int e = t; e < cnt; e += 256) {
      ull r = bp[e];
      int local = (int)((r >> 16) & 255);
      int srcv = (int)(r & 0xFFFFu);
      float w = (float)(unsigned)(r >> 24) * (1.0f / 67108864.0f);
      int slot = atomicAdd(&lcur[local * 8 + src_tile(srcv)], 1);
      cv[slot] = pack_rec(srcv, w);
    }
  } else {
    __shared__ int lhist[64], lbase[64];
    if (t < 64) lhist[t] = 0;
    __syncthreads();
    int i = (bid - (625 + NBKT)) * 256 + t;
    bool valid = (i < N);
    int bin = 0, myrank = 0;
    if (valid) {
      int c = rowc[i];
      bin = min(c, 63);
      myrank = atomicAdd(&lhist[bin], 1);
    }
    __syncthreads();
    if (t < 64 && lhist[t] > 0) lbase[t] = atomicAdd(&histcur[t], lhist[t]);
    __syncthreads();
    if (valid) perm[lbase[bin] + myrank] = i;
  }
}

// ---- Aggregation + skip + (optional) fused BN stats ----
// QUARTER-WAVE-PER-ROW, plain linear edge walk (R3's proven loop). cv is
// tile-sorted within each row, so co-resident degree-similar blocks gather
// from the same ~1.28 MB hlin src-tile at the same time (L2 phase-locality)
// with zero instruction overhead vs R3.

__global__ __launch_bounds__(256) void k_agg(const uint4* __restrict__ Hu4,
    const int* __restrict__ offs, const unsigned int* __restrict__ cv,
    const float* __restrict__ dis, const float* __restrict__ bias,
    const uint4* __restrict__ x0h, const int* __restrict__ perm,
    int doRelu, int doStats, int outF32,
    _Float16* __restrict__ Hout16, float* __restrict__ Houtf, float* __restrict__ sums) {
  int t = threadIdx.x;
  int sl = t & 15;                       // lane within quarter
  int g = t >> 4;                        // quarter id 0..15
  int row = perm[blockIdx.x * 16 + g];   // degree-sorted row for this quarter
  float4 bv0 = ((const float4*)bias)[sl * 2];
  float4 bv1 = ((const float4*)bias)[sl * 2 + 1];
  const uint4* hp = Hu4 + sl;

  int e0 = offs[row], e1 = offs[row + 1];
  float a[8];
#pragma unroll
  for (int k = 0; k < 8; ++k) a[k] = 0.f;
  for (int eb = e0; eb < e1; eb += 16) {
    int m = min(16, e1 - eb);
    unsigned int rec = 0;
    if (sl < m) rec = cv[eb + sl];
#pragma unroll 8
    for (int j = 0; j < m; ++j) {
      unsigned int rj = __shfl(rec, j, 16);
      int sj = (int)(rj & 0xFFFFu);
      union { unsigned short us; _Float16 h; } vh; vh.us = (unsigned short)(rj >> 16);
      float vj = (float)vh.h;
      union { uint4 u; _Float16 hh[8]; } cu;
      cu.u = hp[(size_t)sj * 16];
#pragma unroll
      for (int k = 0; k < 8; ++k) a[k] = fmaf((float)cu.hh[k], vj, a[k]);
    }
  }
  float dr = dis[row];
  union { uint4 u; _Float16 hh[8]; } xc;
  xc.u = x0h[(size_t)row * 16 + sl];
  float rr[8];
  rr[0] = fmaf(a[0], dr, bv0.x); rr[1] = fmaf(a[1], dr, bv0.y);
  rr[2] = fmaf(a[2], dr, bv0.z); rr[3] = fmaf(a[3], dr, bv0.w);
  rr[4] = fmaf(a[4], dr, bv1.x); rr[5] = fmaf(a[5], dr, bv1.y);
  rr[6] = fmaf(a[6], dr, bv1.z); rr[7] = fmaf(a[7], dr, bv1.w);
  if (doRelu) {
#pragma unroll
    for (int k = 0; k < 8; ++k) rr[k] = fmaxf(rr[k], 0.f);
  }
#pragma unroll
  for (int k = 0; k < 8; ++k) rr[k] += (float)xc.hh[k];
  if (outF32) {
    float4 o0, o1;
    o0.x = rr[0]; o0.y = rr[1]; o0.z = rr[2]; o0.w = rr[3];
    o1.x = rr[4]; o1.y = rr[5]; o1.z = rr[6]; o1.w = rr[7];
    ((float4*)Houtf)[(size_t)row * 32 + sl * 2] = o0;
    ((float4*)Houtf)[(size_t)row * 32 + sl * 2 + 1] = o1;
  } else {
    union { uint4 u; _Float16 hh[8]; } ov;
#pragma unroll
    for (int k = 0; k < 8; ++k) ov.hh[k] = (_Float16)rr[k];
    ((uint4*)Hout16)[(size_t)row * 16 + sl] = ov.u;
  }

  if (doStats) {
    __shared__ float reds[16 * 128], reds2[16 * 128];   // 8 KB + 8 KB
#pragma unroll
    for (int k = 0; k < 8; ++k) {
      reds[g * 128 + sl * 8 + k] = rr[k];
      reds2[g * 128 + sl * 8 + k] = rr[k] * rr[k];
    }
    __syncthreads();
    if (t < 128) {
      float ts = 0.f, ts2 = 0.f;
#pragma unroll
      for (int j2 = 0; j2 < 16; ++j2) { ts += reds[j2 * 128 + t]; ts2 += reds2[j2 * 128 + t]; }
      int rep = blockIdx.x & 7;
      atomicAdd(&sums[rep * 256 + t], ts);
      atomicAdd(&sums[rep * 256 + 128 + t], ts2);
    }
  }
}

// ---------------- final BN apply (derives scale/shift in-block) ----------------

__global__ __launch_bounds__(256) void k_bnapply(float* __restrict__ H,
    const float* __restrict__ sums, const float* __restrict__ gamma,
    const float* __restrict__ beta) {
  __shared__ float scl[128], shf[128];
  int t = threadIdx.x;
  if (t < 128) {
    float s = 0.f, s2 = 0.f;
#pragma unroll
    for (int r = 0; r < 8; ++r) { s += sums[r * 256 + t]; s2 += sums[r * 256 + 128 + t]; }
    float mu = s * (1.0f / N);
    float var = s2 * (1.0f / N) - mu * mu;
    float rs = rsqrtf(var + 1e-5f);
    float sc = gamma[t] * rs;
    scl[t] = sc;
    shf[t] = beta[t] - mu * sc;
  }
  __syncthreads();
  size_t i = (size_t)blockIdx.x * 256 + t;  // float4 index; total N*D/4
  float4 v = ((const float4*)H)[i];
  int c = (int)(i & 31) * 4;
  v.x = fmaf(v.x, scl[c + 0], shf[c + 0]);
  v.y = fmaf(v.y, scl[c + 1], shf[c + 1]);
  v.z = fmaf(v.z, scl[c + 2], shf[c + 2]);
  v.w = fmaf(v.w, scl[c + 3], shf[c + 3]);
  ((float4*)H)[i] = v;
}

// ---------------- launch ----------------

extern "C" void kernel_launch(void* const* d_in, const int* in_sizes, int n_in,
                              void* d_out, int out_size, void* d_ws, size_t ws_size,
                              hipStream_t stream) {
  const float* x     = (const float*)d_in[0];
  const int*   ei    = (const int*)d_in[1];
  const float* ew    = (const float*)d_in[2];
  const float* W     = (const float*)d_in[3];
  const float* b     = (const float*)d_in[4];
  const float* gamma = (const float*)d_in[5];
  const float* beta  = (const float*)d_in[6];
  float* out = (float*)d_out;

  char* ws = (char*)d_ws;
  _Float16* hlin   = (_Float16*)ws;                        // 10,240,000 B
  _Float16* hagg16 = (_Float16*)(ws + 10240000);           // 10,240,000 B
  _Float16* xh     = (_Float16*)(ws + 20480000);           // 10,240,000 B
  // --- contiguous zeroed region @30,720,000: 34,176 B ---
  float* sums4    = (float*)(ws + 30720000);      // 4 x 8 x 256 f32 = 32,768 B
  int*   hist     = (int*)  (ws + 30752768);      // 64 i32
  int*   histcur  = (int*)  (ws + 30753024);      // 64 i32
  int*   bktcnt   = (int*)  (ws + 30753280);      // 157 i32 (pad to 640 B)
  unsigned int* done = (unsigned int*)(ws + 30753920); // 1 u32 (pad to 256 B)
  // --- end zeroed region (30,754,176) ---
  float* dis      = (float*)(ws + 30754176);      // N f32 = 160,000
  int*   offs     = (int*)  (ws + 30914176);      // N+1 i32 (pad 160,016)
  int*   rowc     = (int*)  (ws + 31074192);      // N i32 = 160,000
  unsigned int* cv= (unsigned int*)(ws + 31234192); // (E+N) u32 = 2,720,000 B
  int*   perm     = (int*)  (ws + 33954192);      // N i32 = 160,000
  int*   bsum     = (int*)  (ws + 34114192);      // 157 i32 (pad 640)
  int*   bpre     = (int*)  (ws + 34114832);      // 157 i32 (pad 640)
  _Float16* Wt    = (_Float16*)(ws + 34115472);   // 4x128x128 fp16 = 131,072 B
  ull* binned     = (ull*)  (ws + 34246544);      // 157*5120*8 = 6,430,720 B
  ull* tilecnt    = (ull*)  (ws + 40677264);      // N u64 = 320,000 B

  // ---- one-time prep (graph-capture safe) ----
  k_zero<<<9, 256, 0, stream>>>((uint4*)sums4);
  k_bigprep<<<2913, 256, 0, stream>>>(ei, ew, x, xh, W, Wt, binned, bktcnt);
  k_bstats<<<NBKT, 256, 0, stream>>>(binned, bktcnt, dis, rowc, tilecnt,
                                     bsum, hist, bpre, histcur, done);

  for (int l = 0; l < 4; ++l) {
    const _Float16* xin = (l == 0) ? xh : hagg16;
    if (l == 0) {
      // layer-0 gemm (no BN) + tile-ordered CSR build + degree-sort placement
      k_gemm0_fill<<<625 + NBKT + 157, 256, 0, stream>>>(xin, Wt, dis, hlin,
                                                         rowc, tilecnt, bpre,
                                                         binned, bktcnt,
                                                         cv, offs, histcur, perm);
    } else {
      int useBN = (l == 1 || l == 2) ? 1 : 0;    // layer-3 input: layer 2 had no BN
      const float* sprev = sums4 + (size_t)(l - 1) * 2048;
      k_gemm<<<N / 64, 256, 0, stream>>>(xin, Wt + (size_t)l * 16384, sprev,
                                         gamma + (size_t)(l - 1) * D,
                                         beta + (size_t)(l - 1) * D, useBN, dis, hlin);
    }
    int doStats = (l != 2) ? 1 : 0;              // BN stats for layers 0,1,3
    int doRelu = (l < 3) ? 1 : 0;
    int outF32 = (l == 3) ? 1 : 0;               // final layer -> f32 into d_out
    k_agg<<<AGG_GRID, 256, 0, stream>>>((const uint4*)hlin, offs, cv, dis,
                                        b + (size_t)l * D, (const uint4*)xh, perm,
                                        doRelu, doStats, outF32, hagg16, out,
                                        sums4 + (size_t)l * 2048);
  }
  // final output = BN3(out) in place
  k_bnapply<<<(N * D / 4) / 256, 256, 0, stream>>>(out, sums4 + 3 * 2048,
                                                   gamma + 3 * D, beta + 3 * D);
}